// Round 1
// baseline (154.852 us; speedup 1.0000x reference)
//
#include <hip/hip_runtime.h>
#include <cfloat>
#include <climits>
#include <math.h>

#define NSTREAM 4
#define NCLS    20
#define NGT     (NSTREAM * NCLS)   // 80
#define NBLK    128                // x-blocks for the argmax kernel
#define TPB     256

// ---------------------------------------------------------------------------
// Kernel A: per (stream, class) argmax over R rows.
// grid = (NBLK, 4); each thread keeps 20 running (val, idx) pairs, reading
// rows as 5x float4 (fully coalesced: 64 lanes x 80B contiguous).
// First-occurrence tie-break (smaller row index wins on equal value).
// ---------------------------------------------------------------------------
__global__ __launch_bounds__(TPB) void top_argmax_kernel(
    const float* __restrict__ c0, const float* __restrict__ c1,
    const float* __restrict__ c2, const float* __restrict__ c3,
    float* __restrict__ pv, int* __restrict__ pi, int R)
{
    const float* cls = (blockIdx.y == 0) ? c0 : (blockIdx.y == 1) ? c1
                     : (blockIdx.y == 2) ? c2 : c3;
    const int tid = threadIdx.x;
    const int gid = blockIdx.x * TPB + tid;
    const int stride = gridDim.x * TPB;

    float bv[NCLS];
    int   bi[NCLS];
#pragma unroll
    for (int c = 0; c < NCLS; ++c) { bv[c] = -FLT_MAX; bi[c] = 0; }

    for (int r = gid; r < R; r += stride) {
        const float4* row = reinterpret_cast<const float4*>(cls + (size_t)r * NCLS);
#pragma unroll
        for (int q = 0; q < NCLS / 4; ++q) {
            float4 v = row[q];
            float vals[4] = { v.x, v.y, v.z, v.w };
#pragma unroll
            for (int k = 0; k < 4; ++k) {
                const int c = q * 4 + k;
                if (vals[k] > bv[c]) { bv[c] = vals[k]; bi[c] = r; }
            }
        }
    }

    __shared__ float sv[NCLS][TPB];
    __shared__ int   si[NCLS][TPB];
#pragma unroll
    for (int c = 0; c < NCLS; ++c) { sv[c][tid] = bv[c]; si[c][tid] = bi[c]; }
    __syncthreads();

    for (int off = TPB / 2; off > 0; off >>= 1) {
        if (tid < off) {
#pragma unroll
            for (int c = 0; c < NCLS; ++c) {
                float ov = sv[c][tid + off]; int oi = si[c][tid + off];
                float mv = sv[c][tid];       int mi = si[c][tid];
                if (ov > mv || (ov == mv && oi < mi)) { sv[c][tid] = ov; si[c][tid] = oi; }
            }
        }
        __syncthreads();
    }

    if (tid < NCLS) {
        const int p = blockIdx.y * NCLS + tid;          // pair index s*NCLS+c
        pv[(size_t)p * gridDim.x + blockIdx.x] = sv[tid][0];
        pi[(size_t)p * gridDim.x + blockIdx.x] = si[tid][0];
    }
}

// ---------------------------------------------------------------------------
// Kernel B: reduce per-block partials -> top boxes/scores, run the
// instance selector per class, write gtb/gts/valid to d_out, zero-init bins.
// Single block of 256 threads.
// ---------------------------------------------------------------------------
__global__ __launch_bounds__(TPB) void select_kernel(
    const float* __restrict__ rois,
    const float* __restrict__ pv, const int* __restrict__ pi,
    const int* __restrict__ im_labels,
    float* __restrict__ ws_gtb, float* __restrict__ ws_gts,
    int* __restrict__ ws_valid,
    float* __restrict__ ws_sums, float* __restrict__ ws_cnts,
    float* __restrict__ ws_neg,
    float* __restrict__ d_out, int nblk)
{
    const int tid = threadIdx.x;
    __shared__ float s_box[NGT][4];

    if (tid < NGT) {
        const int s = tid / NCLS;
        const int c = tid % NCLS;
        const float* v  = pv + (size_t)tid * nblk;     // tid == s*NCLS+c
        const int*   ii = pi + (size_t)tid * nblk;
        float best = -FLT_MAX; int bidx = INT_MAX;
        for (int b = 0; b < nblk; ++b) {
            float val = v[b]; int idx = ii[b];
            if (val > best || (val == best && idx < bidx)) { best = val; bidx = idx; }
        }
        const int g = c * NSTREAM + s;                 // gt index (class-major)
        float4 box = reinterpret_cast<const float4*>(rois)[bidx];
        s_box[g][0] = box.x; s_box[g][1] = box.y; s_box[g][2] = box.z; s_box[g][3] = box.w;
        ws_gtb[g * 4 + 0] = box.x; ws_gtb[g * 4 + 1] = box.y;
        ws_gtb[g * 4 + 2] = box.z; ws_gtb[g * 4 + 3] = box.w;
        ws_gts[g] = best;
        // d_out layout: [0]=loss, [1..320]=gtb, [321..400]=gts, [401..480]=valid
        d_out[1 + g * 4 + 0] = box.x; d_out[1 + g * 4 + 1] = box.y;
        d_out[1 + g * 4 + 2] = box.z; d_out[1 + g * 4 + 3] = box.w;
        d_out[1 + NGT * 4 + g] = best;
    }
    if (tid < NGT) { ws_sums[tid] = 0.0f; ws_cnts[tid] = 0.0f; }
    if (tid == 0)  { ws_neg[0] = 0.0f; }
    __syncthreads();

    if (tid < NCLS) {
        const int c = tid;
        const bool present = im_labels[c] > 0;
        float bx[NSTREAM][4], area[NSTREAM];
#pragma unroll
        for (int s = 0; s < NSTREAM; ++s) {
#pragma unroll
            for (int k = 0; k < 4; ++k) bx[s][k] = s_box[c * NSTREAM + s][k];
            area[s] = (bx[s][2] - bx[s][0] + 1.0f) * (bx[s][3] - bx[s][1] + 1.0f);
        }
        bool active[NSTREAM], sel[NSTREAM];
#pragma unroll
        for (int s = 0; s < NSTREAM; ++s) { active[s] = present; sel[s] = false; }

        for (int it = 0; it < NSTREAM; ++it) {
            int m = 0; float best = -FLT_MAX;
#pragma unroll
            for (int s = 0; s < NSTREAM; ++s) {
                float v = active[s] ? area[s] : -FLT_MAX;
                if (v > best) { best = v; m = s; }
            }
            const float bmx1 = bx[m][0], bmy1 = bx[m][1], bmx2 = bx[m][2], bmy2 = bx[m][3];
            const float am = area[m];
            bool nact[NSTREAM];
#pragma unroll
            for (int s = 0; s < NSTREAM; ++s) {
                float x1 = fmaxf(bx[s][0], bmx1), y1 = fmaxf(bx[s][1], bmy1);
                float x2 = fminf(bx[s][2], bmx2), y2 = fminf(bx[s][3], bmy2);
                float iw = fmaxf(x2 - x1 + 1.0f, 0.0f), ih = fmaxf(y2 - y1 + 1.0f, 0.0f);
                float inter = iw * ih;
                float iou = inter / (area[s] + am - inter);
                bool enclosed = (bx[s][0] > bmx1) && (bx[s][1] > bmy1) &&
                                (bx[s][2] < bmx2) && (bx[s][3] < bmy2);
                bool pick = active[s] && (s == m);
                bool keep = active[s] && (iou < 0.1f) && (!enclosed);
                sel[s] = sel[s] || pick || keep;
                nact[s] = active[s] && !((iou > 0.3f) || enclosed || keep);
            }
#pragma unroll
            for (int s = 0; s < NSTREAM; ++s) active[s] = nact[s];
        }
#pragma unroll
        for (int s = 0; s < NSTREAM; ++s) {
            const int g = c * NSTREAM + s;
            ws_valid[g] = sel[s] ? 1 : 0;
            d_out[1 + NGT * 4 + NGT + g] = sel[s] ? 1.0f : 0.0f;
        }
    }
}

// ---------------------------------------------------------------------------
// Kernel C: per-roi IoU argmax against 80 gts (LDS-cached), accumulate
// fg sums/counts per gt and neg term via LDS bins -> 1 global atomic/bin/block.
// ---------------------------------------------------------------------------
__global__ __launch_bounds__(TPB) void assign_kernel(
    const float* __restrict__ rois, const float* __restrict__ clsnew,
    const float* __restrict__ ws_gtb, const float* __restrict__ ws_gts,
    const int* __restrict__ ws_valid,
    float* __restrict__ ws_sums, float* __restrict__ ws_cnts,
    float* __restrict__ ws_neg, int R)
{
    __shared__ float4 s_gt[NGT];
    __shared__ float  s_ga[NGT];
    __shared__ float  s_gs[NGT];
    __shared__ int    s_val[NGT];
    __shared__ float  s_sum[NGT];
    __shared__ float  s_cnt[NGT];
    __shared__ float  s_neg;

    const int tid = threadIdx.x;
    if (tid < NGT) {
        float4 b = reinterpret_cast<const float4*>(ws_gtb)[tid];
        s_gt[tid] = b;
        s_ga[tid] = (b.z - b.x + 1.0f) * (b.w - b.y + 1.0f);
        s_gs[tid] = ws_gts[tid];
        s_val[tid] = ws_valid[tid];
        s_sum[tid] = 0.0f; s_cnt[tid] = 0.0f;
    }
    if (tid == 0) s_neg = 0.0f;
    __syncthreads();

    const int r = blockIdx.x * TPB + tid;
    if (r < R) {
        float4 bb = reinterpret_cast<const float4*>(rois)[r];
        float ab = (bb.z - bb.x + 1.0f) * (bb.w - bb.y + 1.0f);
        float best = -FLT_MAX; int assign = 0;
        for (int g = 0; g < NGT; ++g) {
            float v;
            if (s_val[g]) {
                float4 gt = s_gt[g];
                float x1 = fmaxf(bb.x, gt.x), y1 = fmaxf(bb.y, gt.y);
                float x2 = fminf(bb.z, gt.z), y2 = fminf(bb.w, gt.w);
                float iw = fmaxf(x2 - x1 + 1.0f, 0.0f), ih = fmaxf(y2 - y1 + 1.0f, 0.0f);
                float inter = iw * ih;
                v = inter / (ab + s_ga[g] - inter);
            } else {
                v = -1.0f;
            }
            if (v > best) { best = v; assign = g; }   // first-max tie-break
        }
        if (best >= 0.5f) {                           // fg: !(maxov < FG_THRESH)
            int lab = assign / NSTREAM + 1;           // gt_classes[g] = g/4 + 1
            float pa = clsnew[(size_t)r * (NCLS + 1) + lab];
            pa = fminf(fmaxf(pa, 1e-9f), 1.0f - 1e-9f);
            atomicAdd(&s_sum[assign], pa);
            atomicAdd(&s_cnt[assign], 1.0f);
        } else if (best >= 0.1f) {                    // bg with nonzero weight
            float p0 = clsnew[(size_t)r * (NCLS + 1)];
            p0 = fminf(fmaxf(p0, 1e-9f), 1.0f - 1e-9f);
            atomicAdd(&s_neg, logf(p0) * s_gs[assign]);
        }
    }
    __syncthreads();

    if (tid < NGT) {
        if (s_cnt[tid] != 0.0f) {
            atomicAdd(&ws_sums[tid], s_sum[tid]);
            atomicAdd(&ws_cnts[tid], s_cnt[tid]);
        }
    }
    if (tid == 0 && s_neg != 0.0f) atomicAdd(ws_neg, s_neg);
}

// ---------------------------------------------------------------------------
// Kernel D: finalize loss. Single block, 128 threads.
// ---------------------------------------------------------------------------
__global__ __launch_bounds__(128) void finalize_kernel(
    const float* __restrict__ ws_sums, const float* __restrict__ ws_cnts,
    const float* __restrict__ ws_gts, const int* __restrict__ ws_valid,
    const float* __restrict__ ws_neg, float* __restrict__ d_out, int R)
{
    __shared__ float red[128];
    const int tid = threadIdx.x;
    float t = 0.0f;
    if (tid < NGT) {
        float cnt = ws_cnts[tid];
        if (ws_valid[tid] && cnt > 0.0f) {
            float mean = ws_sums[tid] / fmaxf(cnt, 1.0f);
            t = logf(mean) * cnt * ws_gts[tid];
        }
    }
    red[tid] = t;
    __syncthreads();
    for (int off = 64; off > 0; off >>= 1) {
        if (tid < off) red[tid] += red[tid + off];
        __syncthreads();
    }
    if (tid == 0) {
        float pos = -red[0];
        float neg = -ws_neg[0];
        float denom = fmaxf(800.0f, (float)R);
        d_out[0] = (pos + neg) / denom;
    }
}

// ---------------------------------------------------------------------------
extern "C" void kernel_launch(void* const* d_in, const int* in_sizes, int n_in,
                              void* d_out, int out_size, void* d_ws, size_t ws_size,
                              hipStream_t stream) {
    const float* rois   = (const float*)d_in[0];
    const float* c0     = (const float*)d_in[1];
    const float* c1     = (const float*)d_in[2];
    const float* c2     = (const float*)d_in[3];
    const float* c3     = (const float*)d_in[4];
    const float* clsnew = (const float*)d_in[5];
    const int*   imlab  = (const int*)d_in[6];
    const int R = in_sizes[0] / 4;

    float* ws    = (float*)d_ws;
    float* pv    = ws;                                    // 4*20*NBLK floats
    int*   pi    = (int*)(pv + NSTREAM * NCLS * NBLK);    // 4*20*NBLK ints
    float* gtb   = (float*)(pi + NSTREAM * NCLS * NBLK);  // 320
    float* gts   = gtb + NGT * 4;                         // 80
    int*   valid = (int*)(gts + NGT);                     // 80
    float* sums  = (float*)(valid + NGT);                 // 80
    float* cnts  = sums + NGT;                            // 80
    float* neg   = cnts + NGT;                            // 1

    float* out = (float*)d_out;

    dim3 gridA(NBLK, NSTREAM);
    top_argmax_kernel<<<gridA, TPB, 0, stream>>>(c0, c1, c2, c3, pv, pi, R);
    select_kernel<<<1, TPB, 0, stream>>>(rois, pv, pi, imlab, gtb, gts, valid,
                                         sums, cnts, neg, out, NBLK);
    assign_kernel<<<(R + TPB - 1) / TPB, TPB, 0, stream>>>(rois, clsnew, gtb, gts,
                                                           valid, sums, cnts, neg, R);
    finalize_kernel<<<1, 128, 0, stream>>>(sums, cnts, gts, valid, neg, out, R);
}